// Round 8
// baseline (338.220 us; speedup 1.0000x reference)
//
#include <hip/hip_runtime.h>
#include <hip/hip_bf16.h>
#include <stdint.h>

// Problem constants (fixed by setup_inputs)
#define BATCH    8
#define NTOKB    4096                 // tokens per batch
#define NTOK     (BATCH * NTOKB)     // 32768
#define DIN      512
#define DD       512                 // TOKEN_DIM * NUM_HEADS
#define TD       256                 // TOKEN_DIM
#define SCALE    0.0625f             // 256^-0.5
#define LSTR     36                  // LDS row stride in ushorts (72 B): bank-
                                     // map m*18+q*4 mod 32 is 2-to-1 = free

typedef unsigned short ushortT;
typedef __attribute__((ext_vector_type(8))) short  short8;   // 8 bf16 = 4 VGPR
typedef __attribute__((ext_vector_type(4))) float  f32x4;

union Frag { uint4 u; short8 s; };

__device__ __forceinline__ float bf_lo(uint32_t u) { return __uint_as_float(u << 16); }
__device__ __forceinline__ float bf_hi(uint32_t u) { return __uint_as_float(u & 0xffff0000u); }
// round-to-nearest-even f32 -> bf16
__device__ __forceinline__ ushortT f2bf(float f) {
    uint32_t u = __float_as_uint(f);
    return (ushortT)((u + 0x7fffu + ((u >> 16) & 1u)) >> 16);
}
// two 8-byte LDS reads (x tile has 72B rows; 16B read would be misaligned)
__device__ __forceinline__ short8 lds_frag(const ushortT* p) {
    uint2 a = *reinterpret_cast<const uint2*>(p);
    uint2 b = *reinterpret_cast<const uint2*>(p + 4);
    Frag f; f.u.x = a.x; f.u.y = a.y; f.u.z = b.x; f.u.w = b.y;
    return f.s;
}
// async global->LDS 16B per lane: dest = wave-uniform base + lane*16 (linear!)
__device__ __forceinline__ void gload_lds16(const ushortT* g, ushortT* l) {
    __builtin_amdgcn_global_load_lds(
        (const __attribute__((address_space(1))) uint32_t*)(const void*)g,
        (__attribute__((address_space(3))) uint32_t*)(void*)l,
        16, 0, 0);
}

// ---------------------------------------------------------------------------
// K0: pack weights fp32 -> bf16 chunk-tiled B^T form [chunk][n][k32] (dense),
// with a 16B-slot XOR swizzle baked in: physical slot s of row n holds logical
// k-group (s ^ ((n>>1)&3)). A linear wave-ordered global_load_lds then lands
// the swizzled layout in LDS, and swizzled ds_read starts hit 8 distinct
// banks x 2 lanes = conflict-free (m136: 2-way is free).
// blocks 0..15: Wq, 16..31: Wk (n=512), 32..47: Wr (n=256).
// ---------------------------------------------------------------------------
__global__ __launch_bounds__(256) void packw_kernel(
    const float* __restrict__ Wq, const float* __restrict__ Wk,
    const float* __restrict__ Wr, ushortT* __restrict__ W16)
{
    const int blk = blockIdx.x;
    if (blk < 32) {
        const int mat = blk >> 4, c = blk & 15;
        const float* S = mat ? Wk : Wq;
        ushortT* D = W16 + (size_t)mat * (512 * 512) + (size_t)c * 16384;
        for (int i = threadIdx.x; i < 16384; i += 256) {
            int n = i & 511, p = i >> 9;              // consecutive n -> coalesced read
            int l = ((p >> 3) ^ ((n >> 1) & 3)) * 8 + (p & 7);
            D[n * 32 + p] = f2bf(S[(size_t)(c * 32 + l) * 512 + n]);
        }
    } else {
        const int c = blk - 32;
        ushortT* D = W16 + (size_t)2 * (512 * 512) + (size_t)c * 8192;
        for (int i = threadIdx.x; i < 8192; i += 256) {
            int n = i & 255, p = i >> 8;
            int l = ((p >> 3) ^ ((n >> 1) & 3)) * 8 + (p & 7);
            D[n * 32 + p] = f2bf(Wr[(size_t)(c * 32 + l) * 256 + n]);
        }
    }
}

// ---------------------------------------------------------------------------
// K6: MFMA GEMM + FUSED l2norm + alpha + gq-partial (R0 proven structure,
// grid (512,2), blockIdx.y = mat, ~75us measured):
//   qn/kn = l2norm(x@W + bias) bf16; alpha_raw[t] = SCALE*dot(qn_f32,w_alpha);
//   gq_raw[b,d] += sum_tok alpha_raw[tok]*qn_f32[tok,d]  (UNSCALED by inv_a —
//   deferred into softmax).
// Block = 512 thr (8 waves): 64 tokens x ALL 512 cols. K=512 in 16 chunks.
// Per chunk: {barrier, stage x fp32->bf16 + W via global_load_lds, barrier,
// 16 MFMA}. LDS ~42KB -> 3 blocks/CU.
// ---------------------------------------------------------------------------
__global__ __launch_bounds__(512) void gemm_qk_kernel(
    const float* __restrict__ x, const ushortT* __restrict__ W16,
    const float* __restrict__ bq, const float* __restrict__ bk,
    const float* __restrict__ w_alpha,
    ushortT* __restrict__ qn, ushortT* __restrict__ kn,
    float* __restrict__ alpha_raw, float* __restrict__ gq_raw)
{
    __shared__ __align__(16) ushortT xs[64 * LSTR];    // x tile  [tok][k]  4.5 KB
    __shared__ __align__(16) ushortT wsd[512 * 32];    // W tile linear    32 KB
    __shared__ float rowsq[8][64];
    __shared__ float alphap[8][64];
    __shared__ float rnorm_s[64];
    __shared__ float alpha_sh[64];

    const int tid = threadIdx.x;
    const int mat = blockIdx.y;
    const size_t tok0 = (size_t)blockIdx.x * 64;
    const int b = (int)(blockIdx.x >> 6);              // 64 blocks per batch
    const ushortT* Wb = W16 + (size_t)mat * (512 * 512);
    const float* bias = mat ? bk : bq;
    ushortT* dst = mat ? kn : qn;

    const int lane = tid & 63, w = tid >> 6;    // wave w -> cols [w*64, w*64+64)
    const int m = lane & 15, quad = lane >> 4;

    f32x4 acc[4][4];
    #pragma unroll
    for (int tr = 0; tr < 4; ++tr)
        #pragma unroll
        for (int tc = 0; tc < 4; ++tc) acc[tr][tc] = (f32x4){0.f, 0.f, 0.f, 0.f};

    const int xtok = tid >> 3;                 // 0..63
    const int xkg  = (tid & 7) * 4;            // 0..28
    const float* xsrc = x + (tok0 + xtok) * DIN;

    for (int c = 0; c < 16; ++c) {
        __syncthreads();
        // ---- stage x: 64 tok x 32 k, fp32 -> bf16 (8B writes)
        {
            float4 xv = *reinterpret_cast<const float4*>(xsrc + c * 32 + xkg);
            ushort4 xb;
            xb.x = f2bf(xv.x); xb.y = f2bf(xv.y); xb.z = f2bf(xv.z); xb.w = f2bf(xv.w);
            *reinterpret_cast<ushort4*>(&xs[xtok * LSTR + xkg]) = xb;
        }
        // ---- stage W chunk: 512 n x 32 k bf16 via async DMA, no VGPR roundtrip
        {
            const ushortT* wsrc = Wb + (size_t)c * 16384;
            #pragma unroll
            for (int i = 0; i < 4; ++i) {
                const int region = i * 8 + w;          // 32 regions x 1 KB
                gload_lds16(wsrc + region * 512 + lane * 8, &wsd[region * 512]);
            }
        }
        __syncthreads();   // drains vmcnt(0): DMA'd W visible
        // ---- compute: one K=32 MFMA per (tr,tc)
        {
            short8 af[4], bfv[4];
            #pragma unroll
            for (int tr = 0; tr < 4; ++tr)
                af[tr] = lds_frag(&xs[(tr * 16 + m) * LSTR + quad * 8]);
            #pragma unroll
            for (int tc = 0; tc < 4; ++tc) {
                const int n = w * 64 + tc * 16 + m;
                bfv[tc] = *reinterpret_cast<const short8*>(
                    &wsd[n * 32 + ((quad ^ ((n >> 1) & 3)) * 8)]);
            }
            #pragma unroll
            for (int tr = 0; tr < 4; ++tr)
                #pragma unroll
                for (int tc = 0; tc < 4; ++tc)
                    acc[tr][tc] = __builtin_amdgcn_mfma_f32_16x16x32_bf16(af[tr], bfv[tc], acc[tr][tc], 0, 0, 0);
        }
    }

    // ---- fused epilogue: bias, row ssq + alpha partials, normalize, store
    float biasv[4], wa[4];
    #pragma unroll
    for (int tc = 0; tc < 4; ++tc) {
        biasv[tc] = bias[w * 64 + tc * 16 + m];
        wa[tc] = (mat == 0) ? w_alpha[w * 64 + tc * 16 + m] : 0.f;
    }
    #pragma unroll
    for (int tr = 0; tr < 4; ++tr)
        #pragma unroll
        for (int tc = 0; tc < 4; ++tc)
            #pragma unroll
            for (int reg = 0; reg < 4; ++reg)
                acc[tr][tc][reg] += biasv[tc];

    __syncthreads();   // compute done everywhere before reusing LDS barriers
    #pragma unroll
    for (int tr = 0; tr < 4; ++tr) {
        #pragma unroll
        for (int reg = 0; reg < 4; ++reg) {
            float s = 0.f, a = 0.f;
            #pragma unroll
            for (int tc = 0; tc < 4; ++tc) {
                float v = acc[tr][tc][reg];
                s = fmaf(v, v, s);
                a = fmaf(v, wa[tc], a);
            }
            // reduce over the 16 m-lanes of this quad
            #pragma unroll
            for (int off = 1; off < 16; off <<= 1) {
                s += __shfl_xor(s, off);
                a += __shfl_xor(a, off);
            }
            if (m == 0) {
                rowsq[w][tr * 16 + quad * 4 + reg] = s;
                alphap[w][tr * 16 + quad * 4 + reg] = a;
            }
        }
    }
    __syncthreads();
    if (tid < 64) {
        float ss = 0.f, aa = 0.f;
        #pragma unroll
        for (int w2 = 0; w2 < 8; ++w2) { ss += rowsq[w2][tid]; aa += alphap[w2][tid]; }
        float rn = 1.0f / fmaxf(sqrtf(ss), 1e-12f);
        float av = SCALE * aa * rn;
        rnorm_s[tid] = rn;
        alpha_sh[tid] = av;
        if (mat == 0) alpha_raw[tok0 + tid] = av;
    }
    __syncthreads();
    float gqp[4] = {0.f, 0.f, 0.f, 0.f};
    #pragma unroll
    for (int tr = 0; tr < 4; ++tr) {
        #pragma unroll
        for (int reg = 0; reg < 4; ++reg) {
            const int rloc = tr * 16 + quad * 4 + reg;
            float rn = rnorm_s[rloc];
            float av = alpha_sh[rloc];
            size_t row = tok0 + rloc;
            ushortT* rp = dst + row * DD + w * 64 + m;
            #pragma unroll
            for (int tc = 0; tc < 4; ++tc) {
                float val = acc[tr][tc][reg] * rn;
                rp[tc * 16] = f2bf(val);
                gqp[tc] = fmaf(av, val, gqp[tc]);
            }
        }
    }
    // ---- gq partial: reduce over the 4 quads (rows 0..63 covered), 1 atomic
    // per (wave, tc, m) = 512 atomics/block — same count as the old wsum1.
    if (mat == 0) {
        #pragma unroll
        for (int tc = 0; tc < 4; ++tc) {
            float p = gqp[tc];
            p += __shfl_xor(p, 16);
            p += __shfl_xor(p, 32);
            if (quad == 0)
                atomicAdd(&gq_raw[b * DD + w * 64 + tc * 16 + m], p);
        }
    }
}

// ---------------------------------------------------------------------------
// K4: fused norm + softmax per batch (8 blocks):
//   inv = 1/max(||nrm_in[b,:4096]||,eps)   (phase A — replaces norm_kernel)
//   v   = in[b,:512]*inv  (* mul if given)  -> softmax -> out
//   wb2 = out*wbeta (if given)
//   Wrg = chunk-tiled swizzled bf16 of (out[k] * Wr_orig[k][n]) (if given) —
//         the B-side of out's kn GEMM; layout identical to packw's Wr branch.
// inv-deferral: wsum/gq accumulations are UNSCALED; the per-batch scalar inv
// is applied here (softmax argument scaling, exact same math).
// ---------------------------------------------------------------------------
__global__ __launch_bounds__(256) void fused_softmax_kernel(
    const float* __restrict__ nrm_in, const float* __restrict__ in,
    const float* __restrict__ mul, const float* __restrict__ wbeta,
    const float* __restrict__ Wr_orig,
    float* __restrict__ out, float* __restrict__ wb2,
    ushortT* __restrict__ Wrg)
{
    int b = blockIdx.x, tid = threadIdx.x;
    __shared__ float red[256];
    __shared__ float g_sh[512];
    // ---- phase A: inverse L2 norm over 4096
    float s = 0.f;
    for (int i = tid; i < NTOKB; i += 256) {
        float v = nrm_in[b * NTOKB + i];
        s = fmaf(v, v, s);
    }
    red[tid] = s;
    __syncthreads();
    for (int off = 128; off > 0; off >>= 1) {
        if (tid < off) red[tid] += red[tid + off];
        __syncthreads();
    }
    float inv = 1.0f / fmaxf(sqrtf(red[0]), 1e-12f);
    __syncthreads();
    // ---- phase B: softmax over 512 with premultipliers
    float v0 = in[b * DD + tid] * inv, v1 = in[b * DD + 256 + tid] * inv;
    if (mul) { v0 *= mul[b * DD + tid]; v1 *= mul[b * DD + 256 + tid]; }
    red[tid] = fmaxf(v0, v1);
    __syncthreads();
    for (int off = 128; off > 0; off >>= 1) {
        if (tid < off) red[tid] = fmaxf(red[tid], red[tid + off]);
        __syncthreads();
    }
    float m = red[0];
    __syncthreads();
    float e0 = expf(v0 - m), e1 = expf(v1 - m);
    red[tid] = e0 + e1;
    __syncthreads();
    for (int off = 128; off > 0; off >>= 1) {
        if (tid < off) red[tid] += red[tid + off];
        __syncthreads();
    }
    float rs = 1.0f / red[0];
    float o0 = e0 * rs, o1 = e1 * rs;
    out[b * DD + tid] = o0;
    out[b * DD + 256 + tid] = o1;
    if (wb2) {
        wb2[b * DD + tid]       = o0 * wbeta[tid];
        wb2[b * DD + 256 + tid] = o1 * wbeta[256 + tid];
    }
    // ---- phase C: Wrg[b] = diag(g_k) @ Wr, chunk-tiled+swizzled bf16.
    // Thread owns column n = tid; builds each 64B row-chunk in regs and
    // stores 4x uint4. Wr reads are lane-coalesced (consecutive n).
    if (Wrg) {
        g_sh[tid] = o0; g_sh[256 + tid] = o1;
        __syncthreads();
        const int n = tid;
        ushortT* Db = Wrg + (size_t)b * (512 * 256);
        for (int c = 0; c < 16; ++c) {
            __align__(16) ushortT ov[32];
            #pragma unroll
            for (int p = 0; p < 32; ++p) {
                int l = ((p >> 3) ^ ((n >> 1) & 3)) * 8 + (p & 7);
                int k = c * 32 + l;
                ov[p] = f2bf(g_sh[k] * Wr_orig[(size_t)k * TD + n]);
            }
            uint4* dst4 = reinterpret_cast<uint4*>(Db + (size_t)c * 8192 + (size_t)n * 32);
            const uint4* src4 = reinterpret_cast<const uint4*>(ov);
            dst4[0] = src4[0]; dst4[1] = src4[1];
            dst4[2] = src4[2]; dst4[3] = src4[3];
        }
    }
}

// ---------------------------------------------------------------------------
// K5+K3 fused: per block (512 blocks: b(8) x 64-token segment):
//   phase 1: beta_raw[tok] = SCALE * dot(kn[tok,:], wb2[b,:])  (wave/token)
//   phase 2: h_raw[b,d] += sum_tok beta_raw[tok]*kn[tok,d]     (UNSCALED;
//            inv_b deferred into softmax2)
// kn's 64KB/block is read once from HBM (phase 1, coalesced) and re-read from
// L2/L1 in phase 2 — eliminates wsum2's full 32MB HBM pass + one dispatch.
// ---------------------------------------------------------------------------
__global__ __launch_bounds__(256) void betawsum_kernel(
    const ushortT* __restrict__ kn, const float* __restrict__ wb2,
    float* __restrict__ beta_raw, float* __restrict__ h_raw)
{
    const int blk = blockIdx.x, tid = threadIdx.x;
    const int b = blk >> 6;
    const int i0 = (blk & 63) * 64;
    __shared__ float bs[64];

    const int wave = tid >> 6, lane = tid & 63;
    // wb2 fragment for this lane (same cols used for every token)
    float4 wv0 = *reinterpret_cast<const float4*>(wb2 + b * DD + lane * 8);
    float4 wv1 = *reinterpret_cast<const float4*>(wb2 + b * DD + lane * 8 + 4);

    // ---- phase 1: 16 iterations x 4 waves = 64 token dots
    for (int it = 0; it < 16; ++it) {
        const int t = it * 4 + wave;
        const size_t tok = (size_t)b * NTOKB + i0 + t;
        uint4 kv = *reinterpret_cast<const uint4*>(kn + tok * DD + lane * 8);
        float s = bf_lo(kv.x) * wv0.x + bf_hi(kv.x) * wv0.y
                + bf_lo(kv.y) * wv0.z + bf_hi(kv.y) * wv0.w
                + bf_lo(kv.z) * wv1.x + bf_hi(kv.z) * wv1.y
                + bf_lo(kv.w) * wv1.z + bf_hi(kv.w) * wv1.w;
        #pragma unroll
        for (int off = 32; off > 0; off >>= 1) s += __shfl_xor(s, off);
        if (lane == 0) {
            float bv = SCALE * s;
            bs[t] = bv;
            beta_raw[tok] = bv;
        }
    }
    __syncthreads();

    // ---- phase 2: wsum over the same 64 rows (L2-hot), col pair per thread
    const uint32_t* M32 = reinterpret_cast<const uint32_t*>(kn);
    size_t base = ((size_t)b * NTOKB + i0) * 256 + tid;
    float a0 = 0.f, a1 = 0.f;
    for (int ii = 0; ii < 64; ++ii) {
        uint32_t v = M32[base + (size_t)ii * 256];
        float wv = bs[ii];
        a0 = fmaf(wv, bf_lo(v), a0);
        a1 = fmaf(wv, bf_hi(v), a1);
    }
    atomicAdd(&h_raw[b * DD + 2 * tid],     a0);
    atomicAdd(&h_raw[b * DD + 2 * tid + 1], a1);
}

// ---------------------------------------------------------------------------
// K8: out = qn@Wr + kn@Wrg + br via dual-B MFMA (algebraic split of
// (g_k*kn+qn)@Wr — the g_k scale lives in Wrg = diag(g_k)@Wr, built by
// softmax2). Output fp32.
// Block = 256 thr (4 waves): 64 tokens x 256 cols. K=512 in 16 chunks of 32.
// Per chunk: {barrier, stage qn+kn tiles (PURE bf16 copies, no VALU pack) +
// Wr AND Wrg chunks via DMA, barrier, 32 MFMA/wave}. 2x MFMA per barrier vs
// the old kvi form, and the fmaf/f2bf pack chain is gone. LDS 41KB (grid is
// 512 blocks = 2/CU, unconstrained).
// NOTE: kn ALIASES d_out — all global kn reads happen in barrier-protected
// staging before any epilogue store; blocks own disjoint token ranges.
// ---------------------------------------------------------------------------
__global__ __launch_bounds__(256) void out_mfma_kernel(
    const ushortT* __restrict__ qn, const ushortT* __restrict__ kn,
    const ushortT* __restrict__ WrT, const ushortT* __restrict__ Wrg,
    const float* __restrict__ br, float* __restrict__ out)
{
    __shared__ __align__(16) ushortT qs[64 * LSTR];    // qn tile [tok][k]  4.5 KB
    __shared__ __align__(16) ushortT ks[64 * LSTR];    // kn tile [tok][k]  4.5 KB
    __shared__ __align__(16) ushortT wrs[2 * 256 * 32]; // Wr | Wrg chunks  32 KB

    const int tid = threadIdx.x;
    const size_t tok0 = (size_t)blockIdx.x * 64;
    const int b = (int)(tok0 >> 12);
    const ushortT* Wgb = Wrg + (size_t)b * (512 * 256);

    const int lane = tid & 63, w = tid >> 6;    // wave w -> cols [w*64, w*64+64)
    const int m = lane & 15, quad = lane >> 4;

    f32x4 acc[4][4];
    #pragma unroll
    for (int tr = 0; tr < 4; ++tr)
        #pragma unroll
        for (int tc = 0; tc < 4; ++tc) acc[tr][tc] = (f32x4){0.f, 0.f, 0.f, 0.f};

    const int st  = tid >> 2;           // token 0..63
    const int skg = (tid & 3) * 8;      // k offset 0, 8, 16, 24

    for (int c = 0; c < 16; ++c) {
        __syncthreads();   // prev chunk's compute done
        // ---- stage qn,kn: 64 tok x 32 k each, pure bf16 copies (8B writes)
        {
            const size_t base = (tok0 + st) * DD + c * 32 + skg;
            uint4 qv = *reinterpret_cast<const uint4*>(qn + base);
            uint4 kv = *reinterpret_cast<const uint4*>(kn + base);
            uint2* lq = reinterpret_cast<uint2*>(&qs[st * LSTR + skg]);
            lq[0] = make_uint2(qv.x, qv.y);
            lq[1] = make_uint2(qv.z, qv.w);
            uint2* lk = reinterpret_cast<uint2*>(&ks[st * LSTR + skg]);
            lk[0] = make_uint2(kv.x, kv.y);
            lk[1] = make_uint2(kv.z, kv.w);
        }
        // ---- stage Wr + Wrg chunks: 2 x 256 n x 32 k bf16 via async DMA
        {
            const ushortT* wsrc = WrT + (size_t)c * 8192;
            const ushortT* gsrc = Wgb + (size_t)c * 8192;
            #pragma unroll
            for (int i = 0; i < 4; ++i) {
                const int region = i * 4 + w;          // 16 regions x 1 KB each
                gload_lds16(wsrc + region * 512 + lane * 8, &wrs[region * 512]);
                gload_lds16(gsrc + region * 512 + lane * 8, &wrs[8192 + region * 512]);
            }
        }
        __syncthreads();   // drains vmcnt(0): DMA'd Wr/Wrg visible
        // ---- compute: 32 MFMA/wave (qn x Wr + kn x Wrg)
        {
            short8 aq[4], ak[4], br_[4], bg[4];
            #pragma unroll
            for (int tr = 0; tr < 4; ++tr) {
                aq[tr] = lds_frag(&qs[(tr * 16 + m) * LSTR + quad * 8]);
                ak[tr] = lds_frag(&ks[(tr * 16 + m) * LSTR + quad * 8]);
            }
            #pragma unroll
            for (int tc = 0; tc < 4; ++tc) {
                const int n = w * 64 + tc * 16 + m;
                const int off = n * 32 + ((quad ^ ((n >> 1) & 3)) * 8);
                br_[tc] = *reinterpret_cast<const short8*>(&wrs[off]);
                bg[tc]  = *reinterpret_cast<const short8*>(&wrs[8192 + off]);
            }
            #pragma unroll
            for (int tr = 0; tr < 4; ++tr)
                #pragma unroll
                for (int tc = 0; tc < 4; ++tc) {
                    acc[tr][tc] = __builtin_amdgcn_mfma_f32_16x16x32_bf16(aq[tr], br_[tc], acc[tr][tc], 0, 0, 0);
                    acc[tr][tc] = __builtin_amdgcn_mfma_f32_16x16x32_bf16(ak[tr], bg[tc],  acc[tr][tc], 0, 0, 0);
                }
        }
    }

    // ---- epilogue: + br, store fp32 (overwrites kn alias range for own tokens)
    float brv[4];
    #pragma unroll
    for (int tc = 0; tc < 4; ++tc) brv[tc] = br[w * 64 + tc * 16 + m];
    #pragma unroll
    for (int tr = 0; tr < 4; ++tr) {
        #pragma unroll
        for (int reg = 0; reg < 4; ++reg) {
            size_t row = tok0 + tr * 16 + quad * 4 + reg;
            float* rp = out + row * TD + w * 64 + m;
            #pragma unroll
            for (int tc = 0; tc < 4; ++tc)
                rp[tc * 16] = acc[tr][tc][reg] + brv[tc];
        }
    }
}

// ---------------------------------------------------------------------------
extern "C" void kernel_launch(void* const* d_in, const int* in_sizes, int n_in,
                              void* d_out, int out_size, void* d_ws, size_t ws_size,
                              hipStream_t stream)
{
    const float* x       = (const float*)d_in[0];
    const float* Wq      = (const float*)d_in[1];
    const float* bq      = (const float*)d_in[2];
    const float* Wk      = (const float*)d_in[3];
    const float* bk      = (const float*)d_in[4];
    const float* Wr      = (const float*)d_in[5];
    const float* br      = (const float*)d_in[6];
    const float* w_alpha = (const float*)d_in[7];
    const float* w_beta  = (const float*)d_in[8];
    float* out = (float*)d_out;

    // kn ALIASES d_out (byte-identical token ranges); total ws ~36 MB.
    ushortT* kn = (ushortT*)d_out;

    char* ws = (char*)d_ws;
    ushortT* qn = (ushortT*)ws;        ws += (size_t)NTOK * DD * sizeof(ushortT);      // 32 MiB
    ushortT* W16 = (ushortT*)ws;       ws += (size_t)2 * 512 * 512 * sizeof(ushortT)
                                           + (size_t)512 * 256 * sizeof(ushortT);       // 1.25 MiB (Wq,Wk,Wr)
    ushortT* Wrg = (ushortT*)ws;       ws += (size_t)BATCH * 512 * 256 * sizeof(ushortT); // 2 MiB
    float* alpha_raw = (float*)ws;     ws += (size_t)NTOK * sizeof(float);
    float* beta_raw  = (float*)ws;     ws += (size_t)NTOK * sizeof(float);
    float* gq_raw = (float*)ws;        ws += (size_t)BATCH * DD * sizeof(float);
    float* h_raw  = (float*)ws;        ws += (size_t)BATCH * DD * sizeof(float);  // contiguous w/ gq_raw
    float* g_q    = (float*)ws;        ws += (size_t)BATCH * DD * sizeof(float);
    float* wb2    = (float*)ws;        ws += (size_t)BATCH * DD * sizeof(float);
    float* g_k    = (float*)ws;        ws += (size_t)BATCH * DD * sizeof(float);
    ushortT* WrT = W16 + (size_t)2 * 512 * 512;

    hipMemsetAsync(gq_raw, 0, 2 * BATCH * DD * sizeof(float), stream);  // gq + h

    packw_kernel<<<48, 256, 0, stream>>>(Wq, Wk, Wr, W16);
    gemm_qk_kernel<<<dim3(NTOK / 64, 2), 512, 0, stream>>>(x, W16, bq, bk, w_alpha,
                                                           qn, kn, alpha_raw, gq_raw);
    fused_softmax_kernel<<<BATCH, 256, 0, stream>>>(alpha_raw, gq_raw, nullptr,
                                                    w_beta, nullptr, g_q, wb2, nullptr);
    betawsum_kernel<<<NTOK / 64, 256, 0, stream>>>(kn, wb2, beta_raw, h_raw);
    fused_softmax_kernel<<<BATCH, 256, 0, stream>>>(beta_raw, h_raw, g_q,
                                                    nullptr, Wr, g_k, nullptr, Wrg);
    out_mfma_kernel<<<NTOK / 64, 256, 0, stream>>>(qn, kn, WrT, Wrg, br, out);
}

// Round 9
// 241.577 us; speedup vs baseline: 1.4000x; 1.4000x over previous
//
#include <hip/hip_runtime.h>
#include <hip/hip_bf16.h>
#include <stdint.h>

// Problem constants (fixed by setup_inputs)
#define BATCH    8
#define NTOKB    4096                 // tokens per batch
#define NTOK     (BATCH * NTOKB)     // 32768
#define DIN      512
#define DD       512                 // TOKEN_DIM * NUM_HEADS
#define TD       256                 // TOKEN_DIM
#define SCALE    0.0625f             // 256^-0.5
#define LSTR     36                  // LDS row stride in ushorts (72 B): bank-
                                     // map m*18+q*4 mod 32 is 2-to-1 = free

typedef unsigned short ushortT;
typedef __attribute__((ext_vector_type(8))) short  short8;   // 8 bf16 = 4 VGPR
typedef __attribute__((ext_vector_type(4))) float  f32x4;

union Frag { uint4 u; short8 s; };

__device__ __forceinline__ float bf_lo(uint32_t u) { return __uint_as_float(u << 16); }
__device__ __forceinline__ float bf_hi(uint32_t u) { return __uint_as_float(u & 0xffff0000u); }
// round-to-nearest-even f32 -> bf16
__device__ __forceinline__ ushortT f2bf(float f) {
    uint32_t u = __float_as_uint(f);
    return (ushortT)((u + 0x7fffu + ((u >> 16) & 1u)) >> 16);
}
// two 8-byte LDS reads (x tile has 72B rows; 16B read would be misaligned)
__device__ __forceinline__ short8 lds_frag(const ushortT* p) {
    uint2 a = *reinterpret_cast<const uint2*>(p);
    uint2 b = *reinterpret_cast<const uint2*>(p + 4);
    Frag f; f.u.x = a.x; f.u.y = a.y; f.u.z = b.x; f.u.w = b.y;
    return f.s;
}
// async global->LDS 16B per lane: dest = wave-uniform base + lane*16 (linear!)
__device__ __forceinline__ void gload_lds16(const ushortT* g, ushortT* l) {
    __builtin_amdgcn_global_load_lds(
        (const __attribute__((address_space(1))) uint32_t*)(const void*)g,
        (__attribute__((address_space(3))) uint32_t*)(void*)l,
        16, 0, 0);
}

// ---------------------------------------------------------------------------
// K0: pack weights fp32 -> bf16 chunk-tiled B^T form [chunk][n][k32] (dense),
// with a 16B-slot XOR swizzle baked in: physical slot s of row n holds logical
// k-group (s ^ ((n>>1)&3)). A linear wave-ordered global_load_lds then lands
// the swizzled layout in LDS, and swizzled ds_read starts hit 8 distinct
// banks x 2 lanes = conflict-free (m136: 2-way is free).
// blocks 0..15: Wq, 16..31: Wk (n=512), 32..47: Wr (n=256).
// ---------------------------------------------------------------------------
__global__ __launch_bounds__(256) void packw_kernel(
    const float* __restrict__ Wq, const float* __restrict__ Wk,
    const float* __restrict__ Wr, ushortT* __restrict__ W16)
{
    const int blk = blockIdx.x;
    if (blk < 32) {
        const int mat = blk >> 4, c = blk & 15;
        const float* S = mat ? Wk : Wq;
        ushortT* D = W16 + (size_t)mat * (512 * 512) + (size_t)c * 16384;
        for (int i = threadIdx.x; i < 16384; i += 256) {
            int n = i & 511, p = i >> 9;              // consecutive n -> coalesced read
            int l = ((p >> 3) ^ ((n >> 1) & 3)) * 8 + (p & 7);
            D[n * 32 + p] = f2bf(S[(size_t)(c * 32 + l) * 512 + n]);
        }
    } else {
        const int c = blk - 32;
        ushortT* D = W16 + (size_t)2 * (512 * 512) + (size_t)c * 8192;
        for (int i = threadIdx.x; i < 8192; i += 256) {
            int n = i & 255, p = i >> 8;
            int l = ((p >> 3) ^ ((n >> 1) & 3)) * 8 + (p & 7);
            D[n * 32 + p] = f2bf(Wr[(size_t)(c * 32 + l) * 256 + n]);
        }
    }
}

// ---------------------------------------------------------------------------
// K6: MFMA GEMM + FUSED l2norm + alpha + gq-partial (R0 proven structure,
// grid (512,2), blockIdx.y = mat, ~75us measured):
//   qn/kn = l2norm(x@W + bias) bf16; alpha_raw[t] = SCALE*dot(qn_f32,w_alpha);
//   gq_raw[b,d] += sum_tok alpha_raw[tok]*qn_f32[tok,d]  (UNSCALED by inv_a —
//   deferred into softmax).
// Block = 512 thr (8 waves): 64 tokens x ALL 512 cols. K=512 in 16 chunks.
// Per chunk: {barrier, stage x fp32->bf16 + W via global_load_lds, barrier,
// 16 MFMA}. LDS ~42KB -> 3 blocks/CU.
// ---------------------------------------------------------------------------
__global__ __launch_bounds__(512) void gemm_qk_kernel(
    const float* __restrict__ x, const ushortT* __restrict__ W16,
    const float* __restrict__ bq, const float* __restrict__ bk,
    const float* __restrict__ w_alpha,
    ushortT* __restrict__ qn, ushortT* __restrict__ kn,
    float* __restrict__ alpha_raw, float* __restrict__ gq_raw)
{
    __shared__ __align__(16) ushortT xs[64 * LSTR];    // x tile  [tok][k]  4.5 KB
    __shared__ __align__(16) ushortT wsd[512 * 32];    // W tile linear    32 KB
    __shared__ float rowsq[8][64];
    __shared__ float alphap[8][64];
    __shared__ float rnorm_s[64];
    __shared__ float alpha_sh[64];

    const int tid = threadIdx.x;
    const int mat = blockIdx.y;
    const size_t tok0 = (size_t)blockIdx.x * 64;
    const int b = (int)(blockIdx.x >> 6);              // 64 blocks per batch
    const ushortT* Wb = W16 + (size_t)mat * (512 * 512);
    const float* bias = mat ? bk : bq;
    ushortT* dst = mat ? kn : qn;

    const int lane = tid & 63, w = tid >> 6;    // wave w -> cols [w*64, w*64+64)
    const int m = lane & 15, quad = lane >> 4;

    f32x4 acc[4][4];
    #pragma unroll
    for (int tr = 0; tr < 4; ++tr)
        #pragma unroll
        for (int tc = 0; tc < 4; ++tc) acc[tr][tc] = (f32x4){0.f, 0.f, 0.f, 0.f};

    const int xtok = tid >> 3;                 // 0..63
    const int xkg  = (tid & 7) * 4;            // 0..28
    const float* xsrc = x + (tok0 + xtok) * DIN;

    for (int c = 0; c < 16; ++c) {
        __syncthreads();
        // ---- stage x: 64 tok x 32 k, fp32 -> bf16 (8B writes)
        {
            float4 xv = *reinterpret_cast<const float4*>(xsrc + c * 32 + xkg);
            ushort4 xb;
            xb.x = f2bf(xv.x); xb.y = f2bf(xv.y); xb.z = f2bf(xv.z); xb.w = f2bf(xv.w);
            *reinterpret_cast<ushort4*>(&xs[xtok * LSTR + xkg]) = xb;
        }
        // ---- stage W chunk: 512 n x 32 k bf16 via async DMA, no VGPR roundtrip
        {
            const ushortT* wsrc = Wb + (size_t)c * 16384;
            #pragma unroll
            for (int i = 0; i < 4; ++i) {
                const int region = i * 8 + w;          // 32 regions x 1 KB
                gload_lds16(wsrc + region * 512 + lane * 8, &wsd[region * 512]);
            }
        }
        __syncthreads();   // drains vmcnt(0): DMA'd W visible
        // ---- compute: one K=32 MFMA per (tr,tc)
        {
            short8 af[4], bfv[4];
            #pragma unroll
            for (int tr = 0; tr < 4; ++tr)
                af[tr] = lds_frag(&xs[(tr * 16 + m) * LSTR + quad * 8]);
            #pragma unroll
            for (int tc = 0; tc < 4; ++tc) {
                const int n = w * 64 + tc * 16 + m;
                bfv[tc] = *reinterpret_cast<const short8*>(
                    &wsd[n * 32 + ((quad ^ ((n >> 1) & 3)) * 8)]);
            }
            #pragma unroll
            for (int tr = 0; tr < 4; ++tr)
                #pragma unroll
                for (int tc = 0; tc < 4; ++tc)
                    acc[tr][tc] = __builtin_amdgcn_mfma_f32_16x16x32_bf16(af[tr], bfv[tc], acc[tr][tc], 0, 0, 0);
        }
    }

    // ---- fused epilogue: bias, row ssq + alpha partials, normalize, store
    float biasv[4], wa[4];
    #pragma unroll
    for (int tc = 0; tc < 4; ++tc) {
        biasv[tc] = bias[w * 64 + tc * 16 + m];
        wa[tc] = (mat == 0) ? w_alpha[w * 64 + tc * 16 + m] : 0.f;
    }
    #pragma unroll
    for (int tr = 0; tr < 4; ++tr)
        #pragma unroll
        for (int tc = 0; tc < 4; ++tc)
            #pragma unroll
            for (int reg = 0; reg < 4; ++reg)
                acc[tr][tc][reg] += biasv[tc];

    __syncthreads();   // compute done everywhere before reusing LDS barriers
    #pragma unroll
    for (int tr = 0; tr < 4; ++tr) {
        #pragma unroll
        for (int reg = 0; reg < 4; ++reg) {
            float s = 0.f, a = 0.f;
            #pragma unroll
            for (int tc = 0; tc < 4; ++tc) {
                float v = acc[tr][tc][reg];
                s = fmaf(v, v, s);
                a = fmaf(v, wa[tc], a);
            }
            // reduce over the 16 m-lanes of this quad
            #pragma unroll
            for (int off = 1; off < 16; off <<= 1) {
                s += __shfl_xor(s, off);
                a += __shfl_xor(a, off);
            }
            if (m == 0) {
                rowsq[w][tr * 16 + quad * 4 + reg] = s;
                alphap[w][tr * 16 + quad * 4 + reg] = a;
            }
        }
    }
    __syncthreads();
    if (tid < 64) {
        float ss = 0.f, aa = 0.f;
        #pragma unroll
        for (int w2 = 0; w2 < 8; ++w2) { ss += rowsq[w2][tid]; aa += alphap[w2][tid]; }
        float rn = 1.0f / fmaxf(sqrtf(ss), 1e-12f);
        float av = SCALE * aa * rn;
        rnorm_s[tid] = rn;
        alpha_sh[tid] = av;
        if (mat == 0) alpha_raw[tok0 + tid] = av;
    }
    __syncthreads();
    float gqp[4] = {0.f, 0.f, 0.f, 0.f};
    #pragma unroll
    for (int tr = 0; tr < 4; ++tr) {
        #pragma unroll
        for (int reg = 0; reg < 4; ++reg) {
            const int rloc = tr * 16 + quad * 4 + reg;
            float rn = rnorm_s[rloc];
            float av = alpha_sh[rloc];
            size_t row = tok0 + rloc;
            ushortT* rp = dst + row * DD + w * 64 + m;
            #pragma unroll
            for (int tc = 0; tc < 4; ++tc) {
                float val = acc[tr][tc][reg] * rn;
                rp[tc * 16] = f2bf(val);
                gqp[tc] = fmaf(av, val, gqp[tc]);
            }
        }
    }
    // ---- gq partial: reduce over the 4 quads (rows 0..63 covered), 1 atomic
    // per (wave, tc, m) = 512 atomics/block — same count as the old wsum1.
    if (mat == 0) {
        #pragma unroll
        for (int tc = 0; tc < 4; ++tc) {
            float p = gqp[tc];
            p += __shfl_xor(p, 16);
            p += __shfl_xor(p, 32);
            if (quad == 0)
                atomicAdd(&gq_raw[b * DD + w * 64 + tc * 16 + m], p);
        }
    }
}

// ---------------------------------------------------------------------------
// K4: fused norm + softmax per batch (8 blocks):
//   inv = 1/max(||nrm_in[b,:4096]||,eps)   (phase A — replaces norm_kernel)
//   v   = in[b,:512]*inv  (* mul if given)  -> softmax -> out
//   wb2 = out*wbeta (if given)
// inv-deferral: wsum/gq accumulations are UNSCALED; the per-batch scalar inv
// is applied here (softmax argument scaling, exact same math).
// ---------------------------------------------------------------------------
__global__ __launch_bounds__(256) void fused_softmax_kernel(
    const float* __restrict__ nrm_in, const float* __restrict__ in,
    const float* __restrict__ mul, const float* __restrict__ wbeta,
    float* __restrict__ out, float* __restrict__ wb2)
{
    int b = blockIdx.x, tid = threadIdx.x;
    __shared__ float red[256];
    // ---- phase A: inverse L2 norm over 4096
    float s = 0.f;
    for (int i = tid; i < NTOKB; i += 256) {
        float v = nrm_in[b * NTOKB + i];
        s = fmaf(v, v, s);
    }
    red[tid] = s;
    __syncthreads();
    for (int off = 128; off > 0; off >>= 1) {
        if (tid < off) red[tid] += red[tid + off];
        __syncthreads();
    }
    float inv = 1.0f / fmaxf(sqrtf(red[0]), 1e-12f);
    __syncthreads();
    // ---- phase B: softmax over 512 with premultipliers
    float v0 = in[b * DD + tid] * inv, v1 = in[b * DD + 256 + tid] * inv;
    if (mul) { v0 *= mul[b * DD + tid]; v1 *= mul[b * DD + 256 + tid]; }
    red[tid] = fmaxf(v0, v1);
    __syncthreads();
    for (int off = 128; off > 0; off >>= 1) {
        if (tid < off) red[tid] = fmaxf(red[tid], red[tid + off]);
        __syncthreads();
    }
    float m = red[0];
    __syncthreads();
    float e0 = expf(v0 - m), e1 = expf(v1 - m);
    red[tid] = e0 + e1;
    __syncthreads();
    for (int off = 128; off > 0; off >>= 1) {
        if (tid < off) red[tid] += red[tid + off];
        __syncthreads();
    }
    float rs = 1.0f / red[0];
    float o0 = e0 * rs, o1 = e1 * rs;
    out[b * DD + tid] = o0;
    out[b * DD + 256 + tid] = o1;
    if (wb2) {
        wb2[b * DD + tid]       = o0 * wbeta[tid];
        wb2[b * DD + 256 + tid] = o1 * wbeta[256 + tid];
    }
}

// ---------------------------------------------------------------------------
// K7: Wrg[b] = diag(g_k[b]) @ Wr, chunk-tiled+swizzled bf16 (layout identical
// to packw's Wr branch). Grid (16 chunks, 8 batches) x 256 thr — one (b,c)
// 32k x 256n chunk per block: 32KB coalesced Wr reads, 16KB uint4 stores.
// (R7 lesson: this work inside the 8-block softmax was 113us of pure latency;
// at 128 blocks it's ~4us.)
// ---------------------------------------------------------------------------
__global__ __launch_bounds__(256) void wrg_kernel(
    const float* __restrict__ g_k, const float* __restrict__ Wr_orig,
    ushortT* __restrict__ Wrg)
{
    const int c = blockIdx.x;          // 0..15
    const int b = blockIdx.y;          // 0..7
    const int n = threadIdx.x;         // 0..255
    __shared__ float g_sh[32];
    if (threadIdx.x < 32) g_sh[threadIdx.x] = g_k[b * DD + c * 32 + threadIdx.x];
    __syncthreads();
    __align__(16) ushortT ov[32];
    #pragma unroll
    for (int p = 0; p < 32; ++p) {
        int l = ((p >> 3) ^ ((n >> 1) & 3)) * 8 + (p & 7);
        ov[p] = f2bf(g_sh[l] * Wr_orig[(size_t)(c * 32 + l) * TD + n]);
    }
    uint4* dst4 = reinterpret_cast<uint4*>(
        Wrg + (size_t)b * (512 * 256) + (size_t)c * 8192 + (size_t)n * 32);
    const uint4* src4 = reinterpret_cast<const uint4*>(ov);
    dst4[0] = src4[0]; dst4[1] = src4[1]; dst4[2] = src4[2]; dst4[3] = src4[3];
}

// ---------------------------------------------------------------------------
// K5+K3 fused: per block (512 blocks: b(8) x 64-token segment):
//   phase 1: beta_raw[tok] = SCALE * dot(kn[tok,:], wb2[b,:])  (wave/token)
//   phase 2: h_raw[b,d] += sum_tok beta_raw[tok]*kn[tok,d]     (UNSCALED;
//            inv_b deferred into softmax2)
// kn's 64KB/block is read once from HBM (phase 1, coalesced) and re-read from
// L2/L1 in phase 2 — eliminates wsum2's full 32MB HBM pass + one dispatch.
// ---------------------------------------------------------------------------
__global__ __launch_bounds__(256) void betawsum_kernel(
    const ushortT* __restrict__ kn, const float* __restrict__ wb2,
    float* __restrict__ beta_raw, float* __restrict__ h_raw)
{
    const int blk = blockIdx.x, tid = threadIdx.x;
    const int b = blk >> 6;
    const int i0 = (blk & 63) * 64;
    __shared__ float bs[64];

    const int wave = tid >> 6, lane = tid & 63;
    // wb2 fragment for this lane (same cols used for every token)
    float4 wv0 = *reinterpret_cast<const float4*>(wb2 + b * DD + lane * 8);
    float4 wv1 = *reinterpret_cast<const float4*>(wb2 + b * DD + lane * 8 + 4);

    // ---- phase 1: 16 iterations x 4 waves = 64 token dots
    for (int it = 0; it < 16; ++it) {
        const int t = it * 4 + wave;
        const size_t tok = (size_t)b * NTOKB + i0 + t;
        uint4 kv = *reinterpret_cast<const uint4*>(kn + tok * DD + lane * 8);
        float s = bf_lo(kv.x) * wv0.x + bf_hi(kv.x) * wv0.y
                + bf_lo(kv.y) * wv0.z + bf_hi(kv.y) * wv0.w
                + bf_lo(kv.z) * wv1.x + bf_hi(kv.z) * wv1.y
                + bf_lo(kv.w) * wv1.z + bf_hi(kv.w) * wv1.w;
        #pragma unroll
        for (int off = 32; off > 0; off >>= 1) s += __shfl_xor(s, off);
        if (lane == 0) {
            float bv = SCALE * s;
            bs[t] = bv;
            beta_raw[tok] = bv;
        }
    }
    __syncthreads();

    // ---- phase 2: wsum over the same 64 rows (L2-hot), col pair per thread
    const uint32_t* M32 = reinterpret_cast<const uint32_t*>(kn);
    size_t base = ((size_t)b * NTOKB + i0) * 256 + tid;
    float a0 = 0.f, a1 = 0.f;
    for (int ii = 0; ii < 64; ++ii) {
        uint32_t v = M32[base + (size_t)ii * 256];
        float wv = bs[ii];
        a0 = fmaf(wv, bf_lo(v), a0);
        a1 = fmaf(wv, bf_hi(v), a1);
    }
    atomicAdd(&h_raw[b * DD + 2 * tid],     a0);
    atomicAdd(&h_raw[b * DD + 2 * tid + 1], a1);
}

// ---------------------------------------------------------------------------
// K8: out = qn@Wr + kn@Wrg + br via dual-B MFMA (algebraic split of
// (g_k*kn+qn)@Wr — the g_k scale lives in Wrg = diag(g_k)@Wr). Output fp32.
// Block = 256 thr (4 waves): 64 tokens x 256 cols. K=512 in 16 chunks of 32.
// Per chunk: {barrier, stage qn+kn tiles (PURE bf16 copies, no VALU pack) +
// Wr AND Wrg chunks via DMA, barrier, 32 MFMA/wave}. 2x MFMA per barrier vs
// the old kvi form, and the fmaf/f2bf pack chain is gone. LDS 41KB (grid is
// 512 blocks = 2/CU, unconstrained).
// NOTE: kn ALIASES d_out — all global kn reads happen in barrier-protected
// staging before any epilogue store; blocks own disjoint token ranges.
// ---------------------------------------------------------------------------
__global__ __launch_bounds__(256) void out_mfma_kernel(
    const ushortT* __restrict__ qn, const ushortT* __restrict__ kn,
    const ushortT* __restrict__ WrT, const ushortT* __restrict__ Wrg,
    const float* __restrict__ br, float* __restrict__ out)
{
    __shared__ __align__(16) ushortT qs[64 * LSTR];    // qn tile [tok][k]  4.5 KB
    __shared__ __align__(16) ushortT ks[64 * LSTR];    // kn tile [tok][k]  4.5 KB
    __shared__ __align__(16) ushortT wrs[2 * 256 * 32]; // Wr | Wrg chunks  32 KB

    const int tid = threadIdx.x;
    const size_t tok0 = (size_t)blockIdx.x * 64;
    const int b = (int)(tok0 >> 12);
    const ushortT* Wgb = Wrg + (size_t)b * (512 * 256);

    const int lane = tid & 63, w = tid >> 6;    // wave w -> cols [w*64, w*64+64)
    const int m = lane & 15, quad = lane >> 4;

    f32x4 acc[4][4];
    #pragma unroll
    for (int tr = 0; tr < 4; ++tr)
        #pragma unroll
        for (int tc = 0; tc < 4; ++tc) acc[tr][tc] = (f32x4){0.f, 0.f, 0.f, 0.f};

    const int st  = tid >> 2;           // token 0..63
    const int skg = (tid & 3) * 8;      // k offset 0, 8, 16, 24

    for (int c = 0; c < 16; ++c) {
        __syncthreads();   // prev chunk's compute done
        // ---- stage qn,kn: 64 tok x 32 k each, pure bf16 copies (8B writes)
        {
            const size_t base = (tok0 + st) * DD + c * 32 + skg;
            uint4 qv = *reinterpret_cast<const uint4*>(qn + base);
            uint4 kv = *reinterpret_cast<const uint4*>(kn + base);
            uint2* lq = reinterpret_cast<uint2*>(&qs[st * LSTR + skg]);
            lq[0] = make_uint2(qv.x, qv.y);
            lq[1] = make_uint2(qv.z, qv.w);
            uint2* lk = reinterpret_cast<uint2*>(&ks[st * LSTR + skg]);
            lk[0] = make_uint2(kv.x, kv.y);
            lk[1] = make_uint2(kv.z, kv.w);
        }
        // ---- stage Wr + Wrg chunks: 2 x 256 n x 32 k bf16 via async DMA
        {
            const ushortT* wsrc = WrT + (size_t)c * 8192;
            const ushortT* gsrc = Wgb + (size_t)c * 8192;
            #pragma unroll
            for (int i = 0; i < 4; ++i) {
                const int region = i * 4 + w;          // 16 regions x 1 KB each
                gload_lds16(wsrc + region * 512 + lane * 8, &wrs[region * 512]);
                gload_lds16(gsrc + region * 512 + lane * 8, &wrs[8192 + region * 512]);
            }
        }
        __syncthreads();   // drains vmcnt(0): DMA'd Wr/Wrg visible
        // ---- compute: 32 MFMA/wave (qn x Wr + kn x Wrg)
        {
            short8 aq[4], ak[4], br_[4], bg[4];
            #pragma unroll
            for (int tr = 0; tr < 4; ++tr) {
                aq[tr] = lds_frag(&qs[(tr * 16 + m) * LSTR + quad * 8]);
                ak[tr] = lds_frag(&ks[(tr * 16 + m) * LSTR + quad * 8]);
            }
            #pragma unroll
            for (int tc = 0; tc < 4; ++tc) {
                const int n = w * 64 + tc * 16 + m;
                const int off = n * 32 + ((quad ^ ((n >> 1) & 3)) * 8);
                br_[tc] = *reinterpret_cast<const short8*>(&wrs[off]);
                bg[tc]  = *reinterpret_cast<const short8*>(&wrs[8192 + off]);
            }
            #pragma unroll
            for (int tr = 0; tr < 4; ++tr)
                #pragma unroll
                for (int tc = 0; tc < 4; ++tc) {
                    acc[tr][tc] = __builtin_amdgcn_mfma_f32_16x16x32_bf16(aq[tr], br_[tc], acc[tr][tc], 0, 0, 0);
                    acc[tr][tc] = __builtin_amdgcn_mfma_f32_16x16x32_bf16(ak[tr], bg[tc],  acc[tr][tc], 0, 0, 0);
                }
        }
    }

    // ---- epilogue: + br, store fp32 (overwrites kn alias range for own tokens)
    float brv[4];
    #pragma unroll
    for (int tc = 0; tc < 4; ++tc) brv[tc] = br[w * 64 + tc * 16 + m];
    #pragma unroll
    for (int tr = 0; tr < 4; ++tr) {
        #pragma unroll
        for (int reg = 0; reg < 4; ++reg) {
            size_t row = tok0 + tr * 16 + quad * 4 + reg;
            float* rp = out + row * TD + w * 64 + m;
            #pragma unroll
            for (int tc = 0; tc < 4; ++tc)
                rp[tc * 16] = acc[tr][tc][reg] + brv[tc];
        }
    }
}

// ---------------------------------------------------------------------------
extern "C" void kernel_launch(void* const* d_in, const int* in_sizes, int n_in,
                              void* d_out, int out_size, void* d_ws, size_t ws_size,
                              hipStream_t stream)
{
    const float* x       = (const float*)d_in[0];
    const float* Wq      = (const float*)d_in[1];
    const float* bq      = (const float*)d_in[2];
    const float* Wk      = (const float*)d_in[3];
    const float* bk      = (const float*)d_in[4];
    const float* Wr      = (const float*)d_in[5];
    const float* br      = (const float*)d_in[6];
    const float* w_alpha = (const float*)d_in[7];
    const float* w_beta  = (const float*)d_in[8];
    float* out = (float*)d_out;

    // kn ALIASES d_out (byte-identical token ranges); total ws ~36 MB.
    ushortT* kn = (ushortT*)d_out;

    char* ws = (char*)d_ws;
    ushortT* qn = (ushortT*)ws;        ws += (size_t)NTOK * DD * sizeof(ushortT);      // 32 MiB
    ushortT* W16 = (ushortT*)ws;       ws += (size_t)2 * 512 * 512 * sizeof(ushortT)
                                           + (size_t)512 * 256 * sizeof(ushortT);       // 1.25 MiB (Wq,Wk,Wr)
    ushortT* Wrg = (ushortT*)ws;       ws += (size_t)BATCH * 512 * 256 * sizeof(ushortT); // 2 MiB
    float* alpha_raw = (float*)ws;     ws += (size_t)NTOK * sizeof(float);
    float* beta_raw  = (float*)ws;     ws += (size_t)NTOK * sizeof(float);
    float* gq_raw = (float*)ws;        ws += (size_t)BATCH * DD * sizeof(float);
    float* h_raw  = (float*)ws;        ws += (size_t)BATCH * DD * sizeof(float);  // contiguous w/ gq_raw
    float* g_q    = (float*)ws;        ws += (size_t)BATCH * DD * sizeof(float);
    float* wb2    = (float*)ws;        ws += (size_t)BATCH * DD * sizeof(float);
    float* g_k    = (float*)ws;        ws += (size_t)BATCH * DD * sizeof(float);
    ushortT* WrT = W16 + (size_t)2 * 512 * 512;

    hipMemsetAsync(gq_raw, 0, 2 * BATCH * DD * sizeof(float), stream);  // gq + h

    packw_kernel<<<48, 256, 0, stream>>>(Wq, Wk, Wr, W16);
    gemm_qk_kernel<<<dim3(NTOK / 64, 2), 512, 0, stream>>>(x, W16, bq, bk, w_alpha,
                                                           qn, kn, alpha_raw, gq_raw);
    fused_softmax_kernel<<<BATCH, 256, 0, stream>>>(alpha_raw, gq_raw, nullptr,
                                                    w_beta, g_q, wb2);
    betawsum_kernel<<<NTOK / 64, 256, 0, stream>>>(kn, wb2, beta_raw, h_raw);
    fused_softmax_kernel<<<BATCH, 256, 0, stream>>>(beta_raw, h_raw, g_q,
                                                    nullptr, g_k, nullptr);
    wrg_kernel<<<dim3(16, BATCH), 256, 0, stream>>>(g_k, Wr, Wrg);
    out_mfma_kernel<<<NTOK / 64, 256, 0, stream>>>(qn, kn, WrT, Wrg, br, out);
}